// Round 2
// baseline (2811.678 us; speedup 1.0000x reference)
//
#include <hip/hip_runtime.h>
#include <hip/hip_bf16.h>

#define H_DIM 2048
#define I_DIM 4096
#define NE 8
#define NT 1024

#define BM 128
#define BN 64
#define BK 32

typedef __bf16 bf16x8 __attribute__((ext_vector_type(8)));
typedef float f32x4 __attribute__((ext_vector_type(4)));
typedef unsigned short u16x8 __attribute__((ext_vector_type(8)));

__device__ __forceinline__ unsigned short f2bf(float f) {
  return __builtin_bit_cast(unsigned short, (__bf16)f);
}

// ---------------- router: 1 wave per token ----------------
__global__ __launch_bounds__(256) void router_kernel(
    const float* __restrict__ x, const float* __restrict__ rw,
    float* __restrict__ rs_out, int* __restrict__ expert_of,
    float* __restrict__ score_of, int* __restrict__ counts)
{
  const int lane = threadIdx.x & 63;
  const int wv = threadIdx.x >> 6;
  const int t = blockIdx.x * 4 + wv;
  float acc[NE];
#pragma unroll
  for (int e = 0; e < NE; ++e) acc[e] = 0.f;
  const float* xr = x + (size_t)t * H_DIM;
  for (int h0 = 0; h0 < H_DIM; h0 += 64) {
    const float xv = xr[h0 + lane];
    const float* rwp = rw + (size_t)(h0 + lane) * NE;
    const f32x4 r0 = *(const f32x4*)rwp;
    const f32x4 r1 = *(const f32x4*)(rwp + 4);
#pragma unroll
    for (int e = 0; e < 4; ++e) { acc[e] += xv * r0[e]; acc[e + 4] += xv * r1[e]; }
  }
#pragma unroll
  for (int e = 0; e < NE; ++e) {
    acc[e] += __shfl_xor(acc[e], 32, 64);
    acc[e] += __shfl_xor(acc[e], 16, 64);
    acc[e] += __shfl_xor(acc[e], 8, 64);
    acc[e] += __shfl_xor(acc[e], 4, 64);
    acc[e] += __shfl_xor(acc[e], 2, 64);
    acc[e] += __shfl_xor(acc[e], 1, 64);
  }
  int best = 0; float bv = acc[0];
#pragma unroll
  for (int e = 1; e < NE; ++e) if (acc[e] > bv) { bv = acc[e]; best = e; }
  const float score = 1.f / (1.f + __expf(-bv));
  if (lane < NE) rs_out[(size_t)lane * NT + t] = (lane == best) ? score : 0.f;
  if (lane == 0) {
    expert_of[t] = best;
    score_of[t] = score;
    atomicAdd(&counts[best], 1);
  }
}

// ---------------- offsets (exclusive prefix over 8 counts) ----------------
__global__ void offsets_kernel(const int* __restrict__ counts,
                               int* __restrict__ offsets, int* __restrict__ cursor)
{
  if (threadIdx.x == 0) {
    int run = 0;
#pragma unroll
    for (int e = 0; e < NE; ++e) { offsets[e] = run; run += counts[e]; cursor[e] = 0; }
  }
}

// ---------------- scatter tokens into per-expert groups ----------------
__global__ void scatter_kernel(const int* __restrict__ expert_of,
                               const int* __restrict__ offsets,
                               int* __restrict__ cursor, int* __restrict__ perm)
{
  const int t = blockIdx.x * 256 + threadIdx.x;
  const int e = expert_of[t];
  const int p = atomicAdd(&cursor[e], 1);
  perm[offsets[e] + p] = t;
}

// ---------------- gather: bf16 x (shared) + score-scaled grouped bf16 x (routed) ----------------
__global__ __launch_bounds__(256) void gather_kernel(
    const float* __restrict__ x, const int* __restrict__ perm,
    const float* __restrict__ score_of, unsigned short* __restrict__ xb,
    unsigned short* __restrict__ xs)
{
  const int b = blockIdx.x;
  const int c = threadIdx.x * 8;
  const int src = perm[b];
  const float s = score_of[src];
  const float* xrow = x + (size_t)b * H_DIM + c;
  const float* srow = x + (size_t)src * H_DIM + c;
  u16x8 vb, vs;
#pragma unroll
  for (int j = 0; j < 8; ++j) {
    vb[j] = f2bf(xrow[j]);
    vs[j] = f2bf(srow[j] * s);
  }
  *(u16x8*)&xb[(size_t)b * H_DIM + c] = vb;
  *(u16x8*)&xs[(size_t)b * H_DIM + c] = vs;
}

// ================= GEMM1: act = silu(X@Wg) * (X@Wu) =================
// Barrier-free: W (A-operand) per-lane scalar dwords from HBM,
// X (B-operand) per-lane dwordx4 from global (L2-resident, 64x reuse).
// Register software-pipeline, 1 K-step prefetch depth (stages A/B).

#define LOADW1(WG, WU, K0) do {                                          \
  const float* _g = wgbase + (size_t)(K0) * ldw;                         \
  const float* _u = wubase + (size_t)(K0) * ldw;                         \
  _Pragma("unroll")                                                      \
  for (int j = 0; j < 8; ++j) { WG[j] = _g[(size_t)j * ldw];             \
                                WU[j] = _u[(size_t)j * ldw]; }           \
} while (0)

#define LOADX1(XF, K0) do {                                              \
  _Pragma("unroll")                                                      \
  for (int mb = 0; mb < 8; ++mb)                                         \
    XF[mb] = *(const u16x8*)(xptr[mb] + (K0));                           \
} while (0)

#define COMPUTE1(WG, WU, XF) do {                                        \
  bf16x8 _wgf, _wuf;                                                     \
  _Pragma("unroll")                                                      \
  for (int j = 0; j < 8; ++j) { _wgf[j] = (__bf16)WG[j];                 \
                                _wuf[j] = (__bf16)WU[j]; }               \
  _Pragma("unroll")                                                      \
  for (int mb = 0; mb < 8; ++mb) {                                       \
    const bf16x8 _xf = __builtin_bit_cast(bf16x8, XF[mb]);               \
    accg[mb] = __builtin_amdgcn_mfma_f32_16x16x32_bf16(_wgf, _xf, accg[mb], 0, 0, 0); \
    accu[mb] = __builtin_amdgcn_mfma_f32_16x16x32_bf16(_wuf, _xf, accu[mb], 0, 0, 0); \
  }                                                                      \
} while (0)

__global__ __launch_bounds__(256) void gemm1_kernel(
    const unsigned short* __restrict__ xs, const unsigned short* __restrict__ xb,
    const float* __restrict__ gup, const float* __restrict__ sgw,
    const float* __restrict__ suw, unsigned short* __restrict__ act_r,
    unsigned short* __restrict__ act_s, const int* __restrict__ counts,
    const int* __restrict__ offsets)
{
  const int e = blockIdx.z;
  int cnt, roff; size_t ldw;
  const unsigned short* X; const float* Wg; const float* Wu; unsigned short* OUT;
  if (e < NE) {
    cnt = counts[e]; roff = offsets[e]; ldw = 2 * I_DIM;
    X = xs; Wg = gup + (size_t)e * H_DIM * 2 * I_DIM; Wu = Wg + I_DIM; OUT = act_r;
  } else {
    cnt = NT; roff = 0; ldw = I_DIM;
    X = xb; Wg = sgw; Wu = suw; OUT = act_s;
  }
  const int m0 = blockIdx.x * BM;
  if (m0 >= cnt) return;
  const int n0 = blockIdx.y * BN;

  const int lane = threadIdx.x & 63, w = threadIdx.x >> 6;
  const int na = n0 + w * 16 + (lane & 15);
  const float* wgbase = Wg + (size_t)((lane >> 4) * 8) * ldw + na;
  const float* wubase = Wu + (size_t)((lane >> 4) * 8) * ldw + na;

  const unsigned short* xptr[8];
#pragma unroll
  for (int mb = 0; mb < 8; ++mb)
    xptr[mb] = X + (size_t)(roff + m0 + mb * 16 + (lane & 15)) * H_DIM + ((lane >> 4) * 8);

  f32x4 accg[8] = {};
  f32x4 accu[8] = {};

  float wgA[8], wuA[8], wgB[8], wuB[8];
  u16x8 xA[8], xB[8];
  LOADW1(wgA, wuA, 0);      LOADX1(xA, 0);
  LOADW1(wgB, wuB, BK);     LOADX1(xB, BK);

  for (int k0 = 0; k0 < H_DIM - 2 * BK; k0 += 2 * BK) {
    COMPUTE1(wgA, wuA, xA);
    LOADW1(wgA, wuA, k0 + 2 * BK);  LOADX1(xA, k0 + 2 * BK);
    COMPUTE1(wgB, wuB, xB);
    LOADW1(wgB, wuB, k0 + 3 * BK);  LOADX1(xB, k0 + 3 * BK);
  }
  COMPUTE1(wgA, wuA, xA);
  COMPUTE1(wgB, wuB, xB);

  // D layout: row(n) = (lane>>4)*4 + reg, col(m) = lane&15   [verified m89/m91]
  const int nw = n0 + w * 16 + ((lane >> 4) * 4);
#pragma unroll
  for (int mb = 0; mb < 8; ++mb) {
    const int m = m0 + mb * 16 + (lane & 15);
    if (m < cnt) {
      unsigned short o[4];
#pragma unroll
      for (int r = 0; r < 4; ++r) {
        const float g = accg[mb][r];
        const float u = accu[mb][r];
        const float sg = g / (1.f + __expf(-g));
        o[r] = f2bf(sg * u);
      }
      uint2 pk;
      pk.x = (unsigned)o[0] | ((unsigned)o[1] << 16);
      pk.y = (unsigned)o[2] | ((unsigned)o[3] << 16);
      *(uint2*)&OUT[(size_t)(roff + m) * I_DIM + nw] = pk;
    }
  }
}

// ================= GEMM2: out[t] (+)= act @ Wd =================

#define LOADW2(WD, K0) do {                                              \
  const float* _d = wdbase + (size_t)(K0) * H_DIM;                       \
  _Pragma("unroll")                                                      \
  for (int j = 0; j < 8; ++j) WD[j] = _d[(size_t)j * H_DIM];             \
} while (0)

#define LOADX2(XF, K0) do {                                              \
  _Pragma("unroll")                                                      \
  for (int mb = 0; mb < 8; ++mb)                                         \
    XF[mb] = *(const u16x8*)(xptr[mb] + (K0));                           \
} while (0)

#define COMPUTE2(WD, XF) do {                                            \
  bf16x8 _wdf;                                                           \
  _Pragma("unroll")                                                      \
  for (int j = 0; j < 8; ++j) _wdf[j] = (__bf16)WD[j];                   \
  _Pragma("unroll")                                                      \
  for (int mb = 0; mb < 8; ++mb) {                                       \
    const bf16x8 _xf = __builtin_bit_cast(bf16x8, XF[mb]);               \
    acc[mb] = __builtin_amdgcn_mfma_f32_16x16x32_bf16(_wdf, _xf, acc[mb], 0, 0, 0); \
  }                                                                      \
} while (0)

__global__ __launch_bounds__(256) void gemm2_kernel(
    const unsigned short* __restrict__ ACT, const float* __restrict__ wd_base,
    float* __restrict__ OUT, const int* __restrict__ counts,
    const int* __restrict__ offsets, const int* __restrict__ perm,
    const int accumulate)
{
  const int e = blockIdx.z;
  const int cnt = counts ? counts[e] : NT;
  const int roff = offsets ? offsets[e] : 0;
  const int m0 = blockIdx.x * BM;
  if (m0 >= cnt) return;
  const int n0 = blockIdx.y * BN;
  const float* Wd = wd_base + (size_t)e * I_DIM * H_DIM;

  const int lane = threadIdx.x & 63, w = threadIdx.x >> 6;
  const int na = n0 + w * 16 + (lane & 15);
  const float* wdbase = Wd + (size_t)((lane >> 4) * 8) * H_DIM + na;

  const unsigned short* xptr[8];
#pragma unroll
  for (int mb = 0; mb < 8; ++mb)
    xptr[mb] = ACT + (size_t)(roff + m0 + mb * 16 + (lane & 15)) * I_DIM + ((lane >> 4) * 8);

  f32x4 acc[8] = {};

  float wdA[8], wdB[8];
  u16x8 xA[8], xB[8];
  LOADW2(wdA, 0);     LOADX2(xA, 0);
  LOADW2(wdB, BK);    LOADX2(xB, BK);

  for (int k0 = 0; k0 < I_DIM - 2 * BK; k0 += 2 * BK) {
    COMPUTE2(wdA, xA);
    LOADW2(wdA, k0 + 2 * BK);  LOADX2(xA, k0 + 2 * BK);
    COMPUTE2(wdB, xB);
    LOADW2(wdB, k0 + 3 * BK);  LOADX2(xB, k0 + 3 * BK);
  }
  COMPUTE2(wdA, xA);
  COMPUTE2(wdB, xB);

  const int nw = n0 + w * 16 + ((lane >> 4) * 4);
#pragma unroll
  for (int mb = 0; mb < 8; ++mb) {
    const int m = m0 + mb * 16 + (lane & 15);
    if (m < cnt) {
      const int t = perm ? perm[roff + m] : m;
      float* orow = OUT + (size_t)t * H_DIM + nw;
      f32x4 v = acc[mb];
      if (accumulate) {
        const f32x4 old = *(const f32x4*)orow;
        v += old;
      }
      *(f32x4*)orow = v;
    }
  }
}

extern "C" void kernel_launch(void* const* d_in, const int* in_sizes, int n_in,
                              void* d_out, int out_size, void* d_ws, size_t ws_size,
                              hipStream_t stream)
{
  const float* x   = (const float*)d_in[0];
  const float* rw  = (const float*)d_in[1];
  const float* gup = (const float*)d_in[2];
  const float* dwn = (const float*)d_in[3];
  const float* sgw = (const float*)d_in[4];
  const float* suw = (const float*)d_in[5];
  const float* sdw = (const float*)d_in[6];
  float* out = (float*)d_out;
  float* rs_out = out + (size_t)NT * H_DIM;   // router_scores [E][T] after out [T][H]

  char* ws = (char*)d_ws;
  int* counts   = (int*)ws;               // 32 B
  int* cursor   = (int*)(ws + 32);        // 32 B
  int* offsets  = (int*)(ws + 64);        // 32 B
  int* expert_of = (int*)(ws + 128);      // 4 KB
  float* score_of = (float*)(ws + 128 + 4096);
  int* perm     = (int*)(ws + 128 + 8192);
  unsigned short* xb    = (unsigned short*)(ws + 16384);       // [T][H] bf16 (4 MB)
  unsigned short* xs    = xb + (size_t)NT * H_DIM;             // grouped scaled (4 MB)
  unsigned short* act_s = xs + (size_t)NT * H_DIM;             // [T][I] bf16 (8 MB)
  unsigned short* act_r = act_s + (size_t)NT * I_DIM;          // [T][I] bf16 (8 MB)

  hipMemsetAsync(counts, 0, 64, stream);
  router_kernel<<<dim3(NT / 4), dim3(256), 0, stream>>>(x, rw, rs_out, expert_of, score_of, counts);
  offsets_kernel<<<dim3(1), dim3(64), 0, stream>>>(counts, offsets, cursor);
  scatter_kernel<<<dim3(NT / 256), dim3(256), 0, stream>>>(expert_of, offsets, cursor, perm);
  gather_kernel<<<dim3(NT), dim3(256), 0, stream>>>(x, perm, score_of, xb, xs);
  gemm1_kernel<<<dim3(NT / BM, I_DIM / BN, NE + 1), dim3(256), 0, stream>>>(
      xs, xb, gup, sgw, suw, act_r, act_s, counts, offsets);
  gemm2_kernel<<<dim3(NT / BM, H_DIM / BN, 1), dim3(256), 0, stream>>>(
      act_s, sdw, out, nullptr, nullptr, nullptr, 0);
  gemm2_kernel<<<dim3(NT / BM, H_DIM / BN, NE), dim3(256), 0, stream>>>(
      act_r, dwn, out, counts, offsets, perm, 1);
}

// Round 3
// 1151.578 us; speedup vs baseline: 2.4416x; 2.4416x over previous
//
#include <hip/hip_runtime.h>
#include <hip/hip_bf16.h>

#define H_DIM 2048
#define I_DIM 4096
#define NE 8
#define NT 1024

#define BM 128
#define BN 64
#define BK 32

typedef __bf16 bf16x8 __attribute__((ext_vector_type(8)));
typedef float f32x4 __attribute__((ext_vector_type(4)));
typedef unsigned short u16x8 __attribute__((ext_vector_type(8)));

__device__ __forceinline__ unsigned short f2bf(float f) {
  return __builtin_bit_cast(unsigned short, (__bf16)f);
}

// async global->LDS, 16B per lane; LDS dest = wave-uniform base + lane*16
__device__ __forceinline__ void gl2lds16(const void* g, void* l) {
  __builtin_amdgcn_global_load_lds(
      (const __attribute__((address_space(1))) unsigned int*)g,
      (__attribute__((address_space(3))) unsigned int*)l, 16, 0, 0);
}

#define VMCNT0() asm volatile("s_waitcnt vmcnt(0)" ::: "memory")

// ---------------- router: 1 wave per token ----------------
__global__ __launch_bounds__(256) void router_kernel(
    const float* __restrict__ x, const float* __restrict__ rw,
    float* __restrict__ rs_out, int* __restrict__ expert_of,
    float* __restrict__ score_of, int* __restrict__ counts)
{
  const int lane = threadIdx.x & 63;
  const int wv = threadIdx.x >> 6;
  const int t = blockIdx.x * 4 + wv;
  float acc[NE];
#pragma unroll
  for (int e = 0; e < NE; ++e) acc[e] = 0.f;
  const float* xr = x + (size_t)t * H_DIM;
  for (int h0 = 0; h0 < H_DIM; h0 += 64) {
    const float xv = xr[h0 + lane];
    const float* rwp = rw + (size_t)(h0 + lane) * NE;
    const f32x4 r0 = *(const f32x4*)rwp;
    const f32x4 r1 = *(const f32x4*)(rwp + 4);
#pragma unroll
    for (int e = 0; e < 4; ++e) { acc[e] += xv * r0[e]; acc[e + 4] += xv * r1[e]; }
  }
#pragma unroll
  for (int e = 0; e < NE; ++e) {
    acc[e] += __shfl_xor(acc[e], 32, 64);
    acc[e] += __shfl_xor(acc[e], 16, 64);
    acc[e] += __shfl_xor(acc[e], 8, 64);
    acc[e] += __shfl_xor(acc[e], 4, 64);
    acc[e] += __shfl_xor(acc[e], 2, 64);
    acc[e] += __shfl_xor(acc[e], 1, 64);
  }
  int best = 0; float bv = acc[0];
#pragma unroll
  for (int e = 1; e < NE; ++e) if (acc[e] > bv) { bv = acc[e]; best = e; }
  const float score = 1.f / (1.f + __expf(-bv));
  if (lane < NE) rs_out[(size_t)lane * NT + t] = (lane == best) ? score : 0.f;
  if (lane == 0) {
    expert_of[t] = best;
    score_of[t] = score;
    atomicAdd(&counts[best], 1);
  }
}

// ---------------- offsets ----------------
__global__ void offsets_kernel(const int* __restrict__ counts,
                               int* __restrict__ offsets, int* __restrict__ cursor)
{
  if (threadIdx.x == 0) {
    int run = 0;
#pragma unroll
    for (int e = 0; e < NE; ++e) { offsets[e] = run; run += counts[e]; cursor[e] = 0; }
  }
}

// ---------------- scatter ----------------
__global__ void scatter_kernel(const int* __restrict__ expert_of,
                               const int* __restrict__ offsets,
                               int* __restrict__ cursor, int* __restrict__ perm)
{
  const int t = blockIdx.x * 256 + threadIdx.x;
  const int e = expert_of[t];
  const int p = atomicAdd(&cursor[e], 1);
  perm[offsets[e] + p] = t;
}

// ---------------- gather ----------------
__global__ __launch_bounds__(256) void gather_kernel(
    const float* __restrict__ x, const int* __restrict__ perm,
    const float* __restrict__ score_of, unsigned short* __restrict__ xb,
    unsigned short* __restrict__ xs)
{
  const int b = blockIdx.x;
  const int c = threadIdx.x * 8;
  const int src = perm[b];
  const float s = score_of[src];
  const float* xrow = x + (size_t)b * H_DIM + c;
  const float* srow = x + (size_t)src * H_DIM + c;
  u16x8 vb, vs;
#pragma unroll
  for (int j = 0; j < 8; ++j) {
    vb[j] = f2bf(xrow[j]);
    vs[j] = f2bf(srow[j] * s);
  }
  *(u16x8*)&xb[(size_t)b * H_DIM + c] = vb;
  *(u16x8*)&xs[(size_t)b * H_DIM + c] = vs;
}

// ================= GEMM1: act = silu(X@Wg) * (X@Wu) =================
// T3 2-phase: STAGE(next) -> COMPUTE(cur) -> vmcnt(0)+barrier.  All staging via
// global_load_lds (16B/lane).  Swizzles (rule 21, inverse-swz source + swz read):
//   X  tile [128][32]bf16: 16B-chunk c' = c ^ ((m>>1)&3)      (b128 reads conflict-free)
//   W  tile [32][64]f32 : 16B-chunk c' = c ^ (((k>>3)&3)<<1)  (b32 strided reads 2-way)
__global__ __launch_bounds__(256) void gemm1_kernel(
    const unsigned short* __restrict__ xs, const unsigned short* __restrict__ xb,
    const float* __restrict__ gup, const float* __restrict__ sgw,
    const float* __restrict__ suw, unsigned short* __restrict__ act_r,
    unsigned short* __restrict__ act_s, const int* __restrict__ counts,
    const int* __restrict__ offsets)
{
  const int e = blockIdx.z;
  int cnt, roff; size_t ldw;
  const unsigned short* X; const float* Wg; const float* Wu; unsigned short* OUT;
  if (e < NE) {
    cnt = counts[e]; roff = offsets[e]; ldw = 2 * I_DIM;
    X = xs; Wg = gup + (size_t)e * H_DIM * 2 * I_DIM; Wu = Wg + I_DIM; OUT = act_r;
  } else {
    cnt = NT; roff = 0; ldw = I_DIM;
    X = xb; Wg = sgw; Wu = suw; OUT = act_s;
  }
  const int m0 = blockIdx.x * BM;
  if (m0 >= cnt) return;
  const int n0 = blockIdx.y * BN;

  __shared__ char lds[49152];
  char* const xl  = lds;            // [2][8192]: X bf16 [128][32]
  char* const wgl = lds + 16384;    // [2][8192]: Wg f32 [32][64]
  char* const wul = lds + 32768;    // [2][8192]: Wu f32 [32][64]

  const int tid = threadIdx.x, lane = tid & 63, w = tid >> 6;

  // 24 staging slots (8 X, 8 Wg, 8 Wu), 6 per wave
  const char* sp[6]; size_t inc[6]; char* dstb[6];
#pragma unroll
  for (int s = 0; s < 6; ++s) {
    const int g = w * 6 + s;
    if (g < 8) {                       // X slot g: rows 16g..16g+15
      const int m = 16 * g + (lane >> 2);
      const int c = lane & 3;
      const int msrc = (m0 + m < cnt) ? (roff + m0 + m) : roff;
      sp[s] = (const char*)(X + (size_t)msrc * H_DIM + ((c ^ ((m >> 1) & 3)) << 3));
      inc[s] = (size_t)BK * 2;
      dstb[s] = xl + g * 1024;
    } else {                           // W slot: rows 4k..4k+3 of [32][64]
      const int ks = (g - 8) & 7;
      const int r = 4 * ks + (lane >> 4);
      const int cs = (lane & 15) ^ (((r >> 3) & 3) << 1);
      const float* Wb = (g < 16) ? Wg : Wu;
      sp[s] = (const char*)(Wb + (size_t)r * ldw + n0 + (cs << 2));
      inc[s] = (size_t)BK * ldw * 4;
      dstb[s] = ((g < 16) ? wgl : wul) + ks * 1024;
    }
  }

#define STAGE1(CUR) do {                                                 \
  _Pragma("unroll")                                                      \
  for (int s = 0; s < 6; ++s) {                                          \
    gl2lds16(sp[s], dstb[s] + (CUR) * 8192);                             \
    sp[s] += inc[s];                                                     \
  }                                                                      \
} while (0)

  const int q = lane >> 4, l15 = lane & 15;
  const int nl = w * 16 + l15;
  const int wro = q * 2048 + ((nl << 2) ^ (q << 5));          // W read base (bytes)
  const int xro = l15 * 64 + ((q ^ ((l15 >> 1) & 3)) << 4);   // X read base (bytes)

  f32x4 accg[8] = {};
  f32x4 accu[8] = {};

#define COMPUTE1(CUR) do {                                               \
  const char* _xb = xl + (CUR) * 8192 + xro;                             \
  const char* _wg = wgl + (CUR) * 8192 + wro;                            \
  const char* _wu = wul + (CUR) * 8192 + wro;                            \
  float _g32[8], _u32[8];                                                \
  _Pragma("unroll")                                                      \
  for (int j = 0; j < 8; ++j) {                                          \
    _g32[j] = *(const float*)(_wg + j * 256);                            \
    _u32[j] = *(const float*)(_wu + j * 256);                            \
  }                                                                      \
  bf16x8 _gf, _uf;                                                       \
  _Pragma("unroll")                                                      \
  for (int j = 0; j < 8; ++j) { _gf[j] = (__bf16)_g32[j];                \
                                _uf[j] = (__bf16)_u32[j]; }              \
  _Pragma("unroll")                                                      \
  for (int mb = 0; mb < 8; ++mb) {                                       \
    const u16x8 _xr = *(const u16x8*)(_xb + mb * 1024);                  \
    const bf16x8 _xf = __builtin_bit_cast(bf16x8, _xr);                  \
    accg[mb] = __builtin_amdgcn_mfma_f32_16x16x32_bf16(_gf, _xf, accg[mb], 0, 0, 0); \
    accu[mb] = __builtin_amdgcn_mfma_f32_16x16x32_bf16(_uf, _xf, accu[mb], 0, 0, 0); \
  }                                                                      \
} while (0)

  STAGE1(0);
  VMCNT0();
  __syncthreads();
  int cur = 0;
  for (int t = 0; t < H_DIM / BK - 1; ++t) {
    STAGE1(cur ^ 1);
    COMPUTE1(cur);
    VMCNT0();
    __syncthreads();
    cur ^= 1;
  }
  COMPUTE1(cur);

  // D layout: row(n) = (lane>>4)*4 + reg, col(m) = lane&15
  const int nw = n0 + w * 16 + (q * 4);
#pragma unroll
  for (int mb = 0; mb < 8; ++mb) {
    const int m = m0 + mb * 16 + l15;
    if (m < cnt) {
      unsigned short o[4];
#pragma unroll
      for (int r = 0; r < 4; ++r) {
        const float g = accg[mb][r];
        const float u = accu[mb][r];
        const float sg = g / (1.f + __expf(-g));
        o[r] = f2bf(sg * u);
      }
      uint2 pk;
      pk.x = (unsigned)o[0] | ((unsigned)o[1] << 16);
      pk.y = (unsigned)o[2] | ((unsigned)o[3] << 16);
      *(uint2*)&OUT[(size_t)(roff + m) * I_DIM + nw] = pk;
    }
  }
}

// ================= GEMM2: out[t] (+)= act @ Wd =================
__global__ __launch_bounds__(256) void gemm2_kernel(
    const unsigned short* __restrict__ ACT, const float* __restrict__ wd_base,
    float* __restrict__ OUT, const int* __restrict__ counts,
    const int* __restrict__ offsets, const int* __restrict__ perm,
    const int accumulate)
{
  const int e = blockIdx.z;
  const int cnt = counts ? counts[e] : NT;
  const int roff = offsets ? offsets[e] : 0;
  const int m0 = blockIdx.x * BM;
  if (m0 >= cnt) return;
  const int n0 = blockIdx.y * BN;
  const float* Wd = wd_base + (size_t)e * I_DIM * H_DIM;

  __shared__ char lds[32768];
  char* const xl  = lds;            // [2][8192]: ACT bf16 [128][32]
  char* const wdl = lds + 16384;    // [2][8192]: Wd f32 [32][64]

  const int tid = threadIdx.x, lane = tid & 63, w = tid >> 6;

  // 16 staging slots (8 X, 8 Wd), 4 per wave
  const char* sp[4]; size_t inc[4]; char* dstb[4];
#pragma unroll
  for (int s = 0; s < 4; ++s) {
    const int g = w * 4 + s;
    if (g < 8) {
      const int m = 16 * g + (lane >> 2);
      const int c = lane & 3;
      const int msrc = (m0 + m < cnt) ? (roff + m0 + m) : roff;
      sp[s] = (const char*)(ACT + (size_t)msrc * I_DIM + ((c ^ ((m >> 1) & 3)) << 3));
      inc[s] = (size_t)BK * 2;
      dstb[s] = xl + g * 1024;
    } else {
      const int ks = (g - 8) & 7;
      const int r = 4 * ks + (lane >> 4);
      const int cs = (lane & 15) ^ (((r >> 3) & 3) << 1);
      sp[s] = (const char*)(Wd + (size_t)r * H_DIM + n0 + (cs << 2));
      inc[s] = (size_t)BK * H_DIM * 4;
      dstb[s] = wdl + ks * 1024;
    }
  }

#define STAGE2(CUR) do {                                                 \
  _Pragma("unroll")                                                      \
  for (int s = 0; s < 4; ++s) {                                          \
    gl2lds16(sp[s], dstb[s] + (CUR) * 8192);                             \
    sp[s] += inc[s];                                                     \
  }                                                                      \
} while (0)

  const int q = lane >> 4, l15 = lane & 15;
  const int nl = w * 16 + l15;
  const int wro = q * 2048 + ((nl << 2) ^ (q << 5));
  const int xro = l15 * 64 + ((q ^ ((l15 >> 1) & 3)) << 4);

  f32x4 acc[8] = {};

#define COMPUTE2(CUR) do {                                               \
  const char* _xb = xl + (CUR) * 8192 + xro;                             \
  const char* _wd = wdl + (CUR) * 8192 + wro;                            \
  float _d32[8];                                                         \
  _Pragma("unroll")                                                      \
  for (int j = 0; j < 8; ++j) _d32[j] = *(const float*)(_wd + j * 256);  \
  bf16x8 _df;                                                            \
  _Pragma("unroll")                                                      \
  for (int j = 0; j < 8; ++j) _df[j] = (__bf16)_d32[j];                  \
  _Pragma("unroll")                                                      \
  for (int mb = 0; mb < 8; ++mb) {                                       \
    const u16x8 _xr = *(const u16x8*)(_xb + mb * 1024);                  \
    const bf16x8 _xf = __builtin_bit_cast(bf16x8, _xr);                  \
    acc[mb] = __builtin_amdgcn_mfma_f32_16x16x32_bf16(_df, _xf, acc[mb], 0, 0, 0); \
  }                                                                      \
} while (0)

  STAGE2(0);
  VMCNT0();
  __syncthreads();
  int cur = 0;
  for (int t = 0; t < I_DIM / BK - 1; ++t) {
    STAGE2(cur ^ 1);
    COMPUTE2(cur);
    VMCNT0();
    __syncthreads();
    cur ^= 1;
  }
  COMPUTE2(cur);

  const int nw = n0 + w * 16 + (q * 4);
#pragma unroll
  for (int mb = 0; mb < 8; ++mb) {
    const int m = m0 + mb * 16 + l15;
    if (m < cnt) {
      const int t = perm ? perm[roff + m] : m;
      float* orow = OUT + (size_t)t * H_DIM + nw;
      f32x4 v = acc[mb];
      if (accumulate) {
        const f32x4 old = *(const f32x4*)orow;
        v += old;
      }
      *(f32x4*)orow = v;
    }
  }
}

extern "C" void kernel_launch(void* const* d_in, const int* in_sizes, int n_in,
                              void* d_out, int out_size, void* d_ws, size_t ws_size,
                              hipStream_t stream)
{
  const float* x   = (const float*)d_in[0];
  const float* rw  = (const float*)d_in[1];
  const float* gup = (const float*)d_in[2];
  const float* dwn = (const float*)d_in[3];
  const float* sgw = (const float*)d_in[4];
  const float* suw = (const float*)d_in[5];
  const float* sdw = (const float*)d_in[6];
  float* out = (float*)d_out;
  float* rs_out = out + (size_t)NT * H_DIM;   // router_scores [E][T] after out [T][H]

  char* ws = (char*)d_ws;
  int* counts   = (int*)ws;               // 32 B
  int* cursor   = (int*)(ws + 32);        // 32 B
  int* offsets  = (int*)(ws + 64);        // 32 B
  int* expert_of = (int*)(ws + 128);      // 4 KB
  float* score_of = (float*)(ws + 128 + 4096);
  int* perm     = (int*)(ws + 128 + 8192);
  unsigned short* xb    = (unsigned short*)(ws + 16384);       // [T][H] bf16 (4 MB)
  unsigned short* xs    = xb + (size_t)NT * H_DIM;             // grouped scaled (4 MB)
  unsigned short* act_s = xs + (size_t)NT * H_DIM;             // [T][I] bf16 (8 MB)
  unsigned short* act_r = act_s + (size_t)NT * I_DIM;          // [T][I] bf16 (8 MB)

  hipMemsetAsync(counts, 0, 64, stream);
  router_kernel<<<dim3(NT / 4), dim3(256), 0, stream>>>(x, rw, rs_out, expert_of, score_of, counts);
  offsets_kernel<<<dim3(1), dim3(64), 0, stream>>>(counts, offsets, cursor);
  scatter_kernel<<<dim3(NT / 256), dim3(256), 0, stream>>>(expert_of, offsets, cursor, perm);
  gather_kernel<<<dim3(NT), dim3(256), 0, stream>>>(x, perm, score_of, xb, xs);
  gemm1_kernel<<<dim3(NT / BM, I_DIM / BN, NE + 1), dim3(256), 0, stream>>>(
      xs, xb, gup, sgw, suw, act_r, act_s, counts, offsets);
  gemm2_kernel<<<dim3(NT / BM, H_DIM / BN, 1), dim3(256), 0, stream>>>(
      act_s, sdw, out, nullptr, nullptr, nullptr, 0);
  gemm2_kernel<<<dim3(NT / BM, H_DIM / BN, NE), dim3(256), 0, stream>>>(
      act_r, dwn, out, counts, offsets, perm, 1);
}

// Round 4
// 1102.867 us; speedup vs baseline: 2.5494x; 1.0442x over previous
//
#include <hip/hip_runtime.h>
#include <hip/hip_bf16.h>

#define H_DIM 2048
#define I_DIM 4096
#define NE 8
#define NT 1024

#define BM 128
#define BN 64
#define BK 32

#define NSTEP1 (H_DIM / BK)   // 64
#define NSTEP2 (I_DIM / BK)   // 128

typedef __bf16 bf16x8 __attribute__((ext_vector_type(8)));
typedef float f32x4 __attribute__((ext_vector_type(4)));
typedef unsigned short u16x8 __attribute__((ext_vector_type(8)));

__device__ __forceinline__ unsigned short f2bf(float f) {
  return __builtin_bit_cast(unsigned short, (__bf16)f);
}

// async global->LDS, 16B per lane; LDS dest = wave-uniform base + lane*16
__device__ __forceinline__ void gl2lds16(const void* g, void* l) {
  __builtin_amdgcn_global_load_lds(
      (const __attribute__((address_space(1))) unsigned int*)g,
      (__attribute__((address_space(3))) unsigned int*)l, 16, 0, 0);
}

#define FENCE() asm volatile("" ::: "memory")
#define BAR() __builtin_amdgcn_s_barrier()

// ---------------- router: 1 wave per token ----------------
__global__ __launch_bounds__(256) void router_kernel(
    const float* __restrict__ x, const float* __restrict__ rw,
    float* __restrict__ rs_out, int* __restrict__ expert_of,
    float* __restrict__ score_of, int* __restrict__ counts)
{
  const int lane = threadIdx.x & 63;
  const int wv = threadIdx.x >> 6;
  const int t = blockIdx.x * 4 + wv;
  float acc[NE];
#pragma unroll
  for (int e = 0; e < NE; ++e) acc[e] = 0.f;
  const float* xr = x + (size_t)t * H_DIM;
  for (int h0 = 0; h0 < H_DIM; h0 += 64) {
    const float xv = xr[h0 + lane];
    const float* rwp = rw + (size_t)(h0 + lane) * NE;
    const f32x4 r0 = *(const f32x4*)rwp;
    const f32x4 r1 = *(const f32x4*)(rwp + 4);
#pragma unroll
    for (int e = 0; e < 4; ++e) { acc[e] += xv * r0[e]; acc[e + 4] += xv * r1[e]; }
  }
#pragma unroll
  for (int e = 0; e < NE; ++e) {
    acc[e] += __shfl_xor(acc[e], 32, 64);
    acc[e] += __shfl_xor(acc[e], 16, 64);
    acc[e] += __shfl_xor(acc[e], 8, 64);
    acc[e] += __shfl_xor(acc[e], 4, 64);
    acc[e] += __shfl_xor(acc[e], 2, 64);
    acc[e] += __shfl_xor(acc[e], 1, 64);
  }
  int best = 0; float bv = acc[0];
#pragma unroll
  for (int e = 1; e < NE; ++e) if (acc[e] > bv) { bv = acc[e]; best = e; }
  const float score = 1.f / (1.f + __expf(-bv));
  if (lane < NE) rs_out[(size_t)lane * NT + t] = (lane == best) ? score : 0.f;
  if (lane == 0) {
    expert_of[t] = best;
    score_of[t] = score;
    atomicAdd(&counts[best], 1);
  }
}

// ---------------- offsets ----------------
__global__ void offsets_kernel(const int* __restrict__ counts,
                               int* __restrict__ offsets, int* __restrict__ cursor)
{
  if (threadIdx.x == 0) {
    int run = 0;
#pragma unroll
    for (int e = 0; e < NE; ++e) { offsets[e] = run; run += counts[e]; cursor[e] = 0; }
  }
}

// ---------------- scatter ----------------
__global__ void scatter_kernel(const int* __restrict__ expert_of,
                               const int* __restrict__ offsets,
                               int* __restrict__ cursor, int* __restrict__ perm)
{
  const int t = blockIdx.x * 256 + threadIdx.x;
  const int e = expert_of[t];
  const int p = atomicAdd(&cursor[e], 1);
  perm[offsets[e] + p] = t;
}

// ---------------- gather ----------------
__global__ __launch_bounds__(256) void gather_kernel(
    const float* __restrict__ x, const int* __restrict__ perm,
    const float* __restrict__ score_of, unsigned short* __restrict__ xb,
    unsigned short* __restrict__ xs)
{
  const int b = blockIdx.x;
  const int c = threadIdx.x * 8;
  const int src = perm[b];
  const float s = score_of[src];
  const float* xrow = x + (size_t)b * H_DIM + c;
  const float* srow = x + (size_t)src * H_DIM + c;
  u16x8 vb, vs;
#pragma unroll
  for (int j = 0; j < 8; ++j) {
    vb[j] = f2bf(xrow[j]);
    vs[j] = f2bf(srow[j] * s);
  }
  *(u16x8*)&xb[(size_t)b * H_DIM + c] = vb;
  *(u16x8*)&xs[(size_t)b * H_DIM + c] = vs;
}

// ================= GEMM1: act = silu(X@Wg) * (X@Wu) =================
// T3/T4: double-buffer, stage(t+1) issued before compute(t); counted
// s_waitcnt vmcnt(6) (next tile's 6 loads STAY IN FLIGHT across the barrier),
// raw s_barrier (no compiler vmcnt(0) drain).  Two barriers/iter (D=2).
__global__ __launch_bounds__(256) void gemm1_kernel(
    const unsigned short* __restrict__ xs, const unsigned short* __restrict__ xb,
    const float* __restrict__ gup, const float* __restrict__ sgw,
    const float* __restrict__ suw, unsigned short* __restrict__ act_r,
    unsigned short* __restrict__ act_s, const int* __restrict__ counts,
    const int* __restrict__ offsets)
{
  const int e = blockIdx.z;
  int cnt, roff; size_t ldw;
  const unsigned short* X; const float* Wg; const float* Wu; unsigned short* OUT;
  if (e < NE) {
    cnt = counts[e]; roff = offsets[e]; ldw = 2 * I_DIM;
    X = xs; Wg = gup + (size_t)e * H_DIM * 2 * I_DIM; Wu = Wg + I_DIM; OUT = act_r;
  } else {
    cnt = NT; roff = 0; ldw = I_DIM;
    X = xb; Wg = sgw; Wu = suw; OUT = act_s;
  }
  const int m0 = blockIdx.x * BM;
  if (m0 >= cnt) return;
  const int n0 = blockIdx.y * BN;

  __shared__ char lds[49152];
  char* const xl  = lds;            // [2][8192]: X bf16 [128][32]
  char* const wgl = lds + 16384;    // [2][8192]: Wg f32 [32][64]
  char* const wul = lds + 32768;    // [2][8192]: Wu f32 [32][64]

  const int tid = threadIdx.x, lane = tid & 63, w = tid >> 6;

  // 24 staging slots (8 X, 8 Wg, 8 Wu), 6 per wave
  const char* sp[6]; size_t inc[6]; char* dstb[6];
#pragma unroll
  for (int s = 0; s < 6; ++s) {
    const int g = w * 6 + s;
    if (g < 8) {                       // X slot g: rows 16g..16g+15
      const int m = 16 * g + (lane >> 2);
      const int c = lane & 3;
      const int msrc = (m0 + m < cnt) ? (roff + m0 + m) : roff;
      sp[s] = (const char*)(X + (size_t)msrc * H_DIM + ((c ^ ((m >> 1) & 3)) << 3));
      inc[s] = (size_t)BK * 2;
      dstb[s] = xl + g * 1024;
    } else {                           // W slot: rows 4k..4k+3 of [32][64]
      const int ks = (g - 8) & 7;
      const int r = 4 * ks + (lane >> 4);
      const int cs = (lane & 15) ^ (((r >> 3) & 3) << 1);
      const float* Wb = (g < 16) ? Wg : Wu;
      sp[s] = (const char*)(Wb + (size_t)r * ldw + n0 + (cs << 2));
      inc[s] = (size_t)BK * ldw * 4;
      dstb[s] = ((g < 16) ? wgl : wul) + ks * 1024;
    }
  }

#define STAGE1(CUR) do {                                                 \
  _Pragma("unroll")                                                      \
  for (int s = 0; s < 6; ++s) {                                          \
    gl2lds16(sp[s], dstb[s] + (CUR) * 8192);                             \
    sp[s] += inc[s];                                                     \
  }                                                                      \
} while (0)

  const int q = lane >> 4, l15 = lane & 15;
  const int nl = w * 16 + l15;
  const int wro = q * 2048 + ((nl << 2) ^ (q << 5));          // W read base (bytes)
  const int xro = l15 * 64 + ((q ^ ((l15 >> 1) & 3)) << 4);   // X read base (bytes)

  f32x4 accg[8] = {};
  f32x4 accu[8] = {};

#define COMPUTE1(CUR) do {                                               \
  const char* _xb = xl + (CUR) * 8192 + xro;                             \
  const char* _wg = wgl + (CUR) * 8192 + wro;                            \
  const char* _wu = wul + (CUR) * 8192 + wro;                            \
  float _g32[8], _u32[8];                                                \
  _Pragma("unroll")                                                      \
  for (int j = 0; j < 8; ++j) {                                          \
    _g32[j] = *(const float*)(_wg + (j >> 2) * 1024 + (j & 3) * 256);    \
    _u32[j] = *(const float*)(_wu + (j >> 2) * 1024 + (j & 3) * 256);    \
  }                                                                      \
  bf16x8 _gf, _uf;                                                       \
  _Pragma("unroll")                                                      \
  for (int j = 0; j < 8; ++j) { _gf[j] = (__bf16)_g32[j];                \
                                _uf[j] = (__bf16)_u32[j]; }              \
  _Pragma("unroll")                                                      \
  for (int mb = 0; mb < 8; ++mb) {                                       \
    const u16x8 _xr = *(const u16x8*)(_xb + mb * 1024);                  \
    const bf16x8 _xf = __builtin_bit_cast(bf16x8, _xr);                  \
    accg[mb] = __builtin_amdgcn_mfma_f32_16x16x32_bf16(_gf, _xf, accg[mb], 0, 0, 0); \
    accu[mb] = __builtin_amdgcn_mfma_f32_16x16x32_bf16(_uf, _xf, accu[mb], 0, 0, 0); \
  }                                                                      \
} while (0)

  STAGE1(0);
  for (int t = 0; t < NSTEP1 - 1; ++t) {
    STAGE1((t + 1) & 1);                          // 6 loads for tile t+1
    asm volatile("s_waitcnt vmcnt(6)" ::: "memory");  // tile t done; t+1 in flight
    BAR();
    FENCE();
    COMPUTE1(t & 1);
    FENCE();
    BAR();                                        // protect buf (t+1)&1 from overwrite
  }
  asm volatile("s_waitcnt vmcnt(0)" ::: "memory");
  BAR();
  FENCE();
  COMPUTE1((NSTEP1 - 1) & 1);

  // D layout: row(n) = (lane>>4)*4 + reg, col(m) = lane&15
  const int nw = n0 + w * 16 + (q * 4);
#pragma unroll
  for (int mb = 0; mb < 8; ++mb) {
    const int m = m0 + mb * 16 + l15;
    if (m < cnt) {
      unsigned short o[4];
#pragma unroll
      for (int r = 0; r < 4; ++r) {
        const float g = accg[mb][r];
        const float u = accu[mb][r];
        const float sg = g / (1.f + __expf(-g));
        o[r] = f2bf(sg * u);
      }
      uint2 pk;
      pk.x = (unsigned)o[0] | ((unsigned)o[1] << 16);
      pk.y = (unsigned)o[2] | ((unsigned)o[3] << 16);
      *(uint2*)&OUT[(size_t)(roff + m) * I_DIM + nw] = pk;
    }
  }
}

// ================= GEMM2: out[t] (+)= act @ Wd =================
// Hybrid ring: X (L2-resident) double-buffered A=1; W (HBM stream) 4-deep A=2.
// vmcnt(6) steady state = {W(t+1), X(t+1), W(t+2)} allowed in flight.
__global__ __launch_bounds__(256) void gemm2_kernel(
    const unsigned short* __restrict__ ACT, const float* __restrict__ wd_base,
    float* __restrict__ OUT, const int* __restrict__ counts,
    const int* __restrict__ offsets, const int* __restrict__ perm,
    const int accumulate)
{
  const int e = blockIdx.z;
  const int cnt = counts ? counts[e] : NT;
  const int roff = offsets ? offsets[e] : 0;
  const int m0 = blockIdx.x * BM;
  if (m0 >= cnt) return;
  const int n0 = blockIdx.y * BN;
  const float* Wd = wd_base + (size_t)e * I_DIM * H_DIM;

  __shared__ char lds[49152];
  char* const xl  = lds;            // [2][8192]: ACT bf16 [128][32]
  char* const wdl = lds + 16384;    // [4][8192]: Wd f32 [32][64]

  const int tid = threadIdx.x, lane = tid & 63, w = tid >> 6;

  // X: 8 slots, 2/wave.  W: 8 slots, 2/wave.
  const char* spx[2]; char* dstx[2];
  const char* spw[2]; char* dstw[2];
#pragma unroll
  for (int s = 0; s < 2; ++s) {
    {
      const int g = w * 2 + s;
      const int m = 16 * g + (lane >> 2);
      const int c = lane & 3;
      const int msrc = (m0 + m < cnt) ? (roff + m0 + m) : roff;
      spx[s] = (const char*)(ACT + (size_t)msrc * I_DIM + ((c ^ ((m >> 1) & 3)) << 3));
      dstx[s] = xl + g * 1024;
    }
    {
      const int ks = w * 2 + s;
      const int r = 4 * ks + (lane >> 4);
      const int cs = (lane & 15) ^ (((r >> 3) & 3) << 1);
      spw[s] = (const char*)(Wd + (size_t)r * H_DIM + n0 + (cs << 2));
      dstw[s] = wdl + ks * 1024;
    }
  }
  const size_t incx = (size_t)BK * 2;
  const size_t incw = (size_t)BK * H_DIM * 4;

#define STAGEX2(CUR) do {                                                \
  _Pragma("unroll")                                                      \
  for (int s = 0; s < 2; ++s) {                                          \
    gl2lds16(spx[s], dstx[s] + (CUR) * 8192);                            \
    spx[s] += incx;                                                      \
  }                                                                      \
} while (0)

#define STAGEW2(CUR) do {                                                \
  _Pragma("unroll")                                                      \
  for (int s = 0; s < 2; ++s) {                                          \
    gl2lds16(spw[s], dstw[s] + (CUR) * 8192);                            \
    spw[s] += incw;                                                      \
  }                                                                      \
} while (0)

  const int q = lane >> 4, l15 = lane & 15;
  const int nl = w * 16 + l15;
  const int wro = q * 2048 + ((nl << 2) ^ (q << 5));
  const int xro = l15 * 64 + ((q ^ ((l15 >> 1) & 3)) << 4);

  f32x4 acc[8] = {};

#define COMPUTE2(BX, BW) do {                                            \
  const char* _xb = xl + (BX) * 8192 + xro;                              \
  const char* _wd = wdl + (BW) * 8192 + wro;                             \
  float _d32[8];                                                         \
  _Pragma("unroll")                                                      \
  for (int j = 0; j < 8; ++j)                                            \
    _d32[j] = *(const float*)(_wd + (j >> 2) * 1024 + (j & 3) * 256);    \
  bf16x8 _df;                                                            \
  _Pragma("unroll")                                                      \
  for (int j = 0; j < 8; ++j) _df[j] = (__bf16)_d32[j];                  \
  _Pragma("unroll")                                                      \
  for (int mb = 0; mb < 8; ++mb) {                                       \
    const u16x8 _xr = *(const u16x8*)(_xb + mb * 1024);                  \
    const bf16x8 _xf = __builtin_bit_cast(bf16x8, _xr);                  \
    acc[mb] = __builtin_amdgcn_mfma_f32_16x16x32_bf16(_df, _xf, acc[mb], 0, 0, 0); \
  }                                                                      \
} while (0)

  // prologue: X(0), W(0), W(1)
  STAGEX2(0);
  STAGEW2(0);
  STAGEW2(1);
  for (int t = 0; t < NSTEP2 - 2; ++t) {
    STAGEX2((t + 1) & 1);                         // X tile t+1 (2 loads)
    STAGEW2((t + 2) & 3);                         // W tile t+2 (2 loads)
    asm volatile("s_waitcnt vmcnt(6)" ::: "memory");  // X(t), W(t) done
    BAR();
    FENCE();
    COMPUTE2(t & 1, t & 3);
    FENCE();
    BAR();
  }
  // t = NSTEP2-2: no W stage left
  STAGEX2((NSTEP2 - 1) & 1);
  asm volatile("s_waitcnt vmcnt(4)" ::: "memory");
  BAR();
  FENCE();
  COMPUTE2((NSTEP2 - 2) & 1, (NSTEP2 - 2) & 3);
  FENCE();
  BAR();
  // t = NSTEP2-1
  asm volatile("s_waitcnt vmcnt(0)" ::: "memory");
  BAR();
  FENCE();
  COMPUTE2((NSTEP2 - 1) & 1, (NSTEP2 - 1) & 3);

  const int nw = n0 + w * 16 + (q * 4);
#pragma unroll
  for (int mb = 0; mb < 8; ++mb) {
    const int m = m0 + mb * 16 + l15;
    if (m < cnt) {
      const int t = perm ? perm[roff + m] : m;
      float* orow = OUT + (size_t)t * H_DIM + nw;
      f32x4 v = acc[mb];
      if (accumulate) {
        const f32x4 old = *(const f32x4*)orow;
        v += old;
      }
      *(f32x4*)orow = v;
    }
  }
}

extern "C" void kernel_launch(void* const* d_in, const int* in_sizes, int n_in,
                              void* d_out, int out_size, void* d_ws, size_t ws_size,
                              hipStream_t stream)
{
  const float* x   = (const float*)d_in[0];
  const float* rw  = (const float*)d_in[1];
  const float* gup = (const float*)d_in[2];
  const float* dwn = (const float*)d_in[3];
  const float* sgw = (const float*)d_in[4];
  const float* suw = (const float*)d_in[5];
  const float* sdw = (const float*)d_in[6];
  float* out = (float*)d_out;
  float* rs_out = out + (size_t)NT * H_DIM;   // router_scores [E][T] after out [T][H]

  char* ws = (char*)d_ws;
  int* counts   = (int*)ws;               // 32 B
  int* cursor   = (int*)(ws + 32);        // 32 B
  int* offsets  = (int*)(ws + 64);        // 32 B
  int* expert_of = (int*)(ws + 128);      // 4 KB
  float* score_of = (float*)(ws + 128 + 4096);
  int* perm     = (int*)(ws + 128 + 8192);
  unsigned short* xb    = (unsigned short*)(ws + 16384);       // [T][H] bf16 (4 MB)
  unsigned short* xs    = xb + (size_t)NT * H_DIM;             // grouped scaled (4 MB)
  unsigned short* act_s = xs + (size_t)NT * H_DIM;             // [T][I] bf16 (8 MB)
  unsigned short* act_r = act_s + (size_t)NT * I_DIM;          // [T][I] bf16 (8 MB)

  hipMemsetAsync(counts, 0, 64, stream);
  router_kernel<<<dim3(NT / 4), dim3(256), 0, stream>>>(x, rw, rs_out, expert_of, score_of, counts);
  offsets_kernel<<<dim3(1), dim3(64), 0, stream>>>(counts, offsets, cursor);
  scatter_kernel<<<dim3(NT / 256), dim3(256), 0, stream>>>(expert_of, offsets, cursor, perm);
  gather_kernel<<<dim3(NT), dim3(256), 0, stream>>>(x, perm, score_of, xb, xs);
  gemm1_kernel<<<dim3(NT / BM, I_DIM / BN, NE + 1), dim3(256), 0, stream>>>(
      xs, xb, gup, sgw, suw, act_r, act_s, counts, offsets);
  gemm2_kernel<<<dim3(NT / BM, H_DIM / BN, 1), dim3(256), 0, stream>>>(
      act_s, sdw, out, nullptr, nullptr, nullptr, 0);
  gemm2_kernel<<<dim3(NT / BM, H_DIM / BN, NE), dim3(256), 0, stream>>>(
      act_r, dwn, out, counts, offsets, perm, 1);
}

// Round 5
// 1101.688 us; speedup vs baseline: 2.5522x; 1.0011x over previous
//
#include <hip/hip_runtime.h>
#include <hip/hip_bf16.h>

#define H_DIM 2048
#define I_DIM 4096
#define NE 8
#define NT 1024

#define BM 128
#define BN 64
#define BK 32

#define NSTEP1 (H_DIM / BK)   // 64
#define NSTEP2 (I_DIM / BK)   // 128

typedef __bf16 bf16x8 __attribute__((ext_vector_type(8)));
typedef float f32x4 __attribute__((ext_vector_type(4)));
typedef unsigned short u16x8 __attribute__((ext_vector_type(8)));

__device__ __forceinline__ unsigned short f2bf(float f) {
  return __builtin_bit_cast(unsigned short, (__bf16)f);
}

// async global->LDS, 16B per lane; LDS dest = wave-uniform base + lane*16
__device__ __forceinline__ void gl2lds16(const void* g, void* l) {
  __builtin_amdgcn_global_load_lds(
      (const __attribute__((address_space(1))) unsigned int*)g,
      (__attribute__((address_space(3))) unsigned int*)l, 16, 0, 0);
}

#define FENCE() asm volatile("" ::: "memory")
#define BAR() __builtin_amdgcn_s_barrier()

// ---------------- router: 1 wave per token ----------------
__global__ __launch_bounds__(256) void router_kernel(
    const float* __restrict__ x, const float* __restrict__ rw,
    float* __restrict__ rs_out, int* __restrict__ expert_of,
    float* __restrict__ score_of, int* __restrict__ counts)
{
  const int lane = threadIdx.x & 63;
  const int wv = threadIdx.x >> 6;
  const int t = blockIdx.x * 4 + wv;
  float acc[NE];
#pragma unroll
  for (int e = 0; e < NE; ++e) acc[e] = 0.f;
  const float* xr = x + (size_t)t * H_DIM;
  for (int h0 = 0; h0 < H_DIM; h0 += 64) {
    const float xv = xr[h0 + lane];
    const float* rwp = rw + (size_t)(h0 + lane) * NE;
    const f32x4 r0 = *(const f32x4*)rwp;
    const f32x4 r1 = *(const f32x4*)(rwp + 4);
#pragma unroll
    for (int e = 0; e < 4; ++e) { acc[e] += xv * r0[e]; acc[e + 4] += xv * r1[e]; }
  }
#pragma unroll
  for (int e = 0; e < NE; ++e) {
    acc[e] += __shfl_xor(acc[e], 32, 64);
    acc[e] += __shfl_xor(acc[e], 16, 64);
    acc[e] += __shfl_xor(acc[e], 8, 64);
    acc[e] += __shfl_xor(acc[e], 4, 64);
    acc[e] += __shfl_xor(acc[e], 2, 64);
    acc[e] += __shfl_xor(acc[e], 1, 64);
  }
  int best = 0; float bv = acc[0];
#pragma unroll
  for (int e = 1; e < NE; ++e) if (acc[e] > bv) { bv = acc[e]; best = e; }
  const float score = 1.f / (1.f + __expf(-bv));
  if (lane < NE) rs_out[(size_t)lane * NT + t] = (lane == best) ? score : 0.f;
  if (lane == 0) {
    expert_of[t] = best;
    score_of[t] = score;
    atomicAdd(&counts[best], 1);
  }
}

// ---------------- offsets ----------------
__global__ void offsets_kernel(const int* __restrict__ counts,
                               int* __restrict__ offsets, int* __restrict__ cursor)
{
  if (threadIdx.x == 0) {
    int run = 0;
#pragma unroll
    for (int e = 0; e < NE; ++e) { offsets[e] = run; run += counts[e]; cursor[e] = 0; }
  }
}

// ---------------- scatter ----------------
__global__ void scatter_kernel(const int* __restrict__ expert_of,
                               const int* __restrict__ offsets,
                               int* __restrict__ cursor, int* __restrict__ perm)
{
  const int t = blockIdx.x * 256 + threadIdx.x;
  const int e = expert_of[t];
  const int p = atomicAdd(&cursor[e], 1);
  perm[offsets[e] + p] = t;
}

// ---------------- gather ----------------
__global__ __launch_bounds__(256) void gather_kernel(
    const float* __restrict__ x, const int* __restrict__ perm,
    const float* __restrict__ score_of, unsigned short* __restrict__ xb,
    unsigned short* __restrict__ xs)
{
  const int b = blockIdx.x;
  const int c = threadIdx.x * 8;
  const int src = perm[b];
  const float s = score_of[src];
  const float* xrow = x + (size_t)b * H_DIM + c;
  const float* srow = x + (size_t)src * H_DIM + c;
  u16x8 vb, vs;
#pragma unroll
  for (int j = 0; j < 8; ++j) {
    vb[j] = f2bf(xrow[j]);
    vs[j] = f2bf(srow[j] * s);
  }
  *(u16x8*)&xb[(size_t)b * H_DIM + c] = vb;
  *(u16x8*)&xs[(size_t)b * H_DIM + c] = vs;
}

// ================= GEMM1: act = silu(X@Wg) * (X@Wu) =================
// T3/T4: double-buffer, stage(t+1) issued before compute(t); counted
// s_waitcnt vmcnt(6) (next tile's 6 loads STAY IN FLIGHT across the barrier),
// raw s_barrier (no compiler vmcnt(0) drain).  Two barriers/iter (D=2).
__global__ __launch_bounds__(256) void gemm1_kernel(
    const unsigned short* __restrict__ xs, const unsigned short* __restrict__ xb,
    const float* __restrict__ gup, const float* __restrict__ sgw,
    const float* __restrict__ suw, unsigned short* __restrict__ act_r,
    unsigned short* __restrict__ act_s, const int* __restrict__ counts,
    const int* __restrict__ offsets)
{
  const int e = blockIdx.z;
  int cnt, roff; size_t ldw;
  const unsigned short* X; const float* Wg; const float* Wu; unsigned short* OUT;
  if (e < NE) {
    cnt = counts[e]; roff = offsets[e]; ldw = 2 * I_DIM;
    X = xs; Wg = gup + (size_t)e * H_DIM * 2 * I_DIM; Wu = Wg + I_DIM; OUT = act_r;
  } else {
    cnt = NT; roff = 0; ldw = I_DIM;
    X = xb; Wg = sgw; Wu = suw; OUT = act_s;
  }
  const int m0 = blockIdx.x * BM;
  if (m0 >= cnt) return;
  const int n0 = blockIdx.y * BN;

  __shared__ char lds[49152];
  char* const xl  = lds;            // [2][8192]: X bf16 [128][32]
  char* const wgl = lds + 16384;    // [2][8192]: Wg f32 [32][64]
  char* const wul = lds + 32768;    // [2][8192]: Wu f32 [32][64]

  const int tid = threadIdx.x, lane = tid & 63, w = tid >> 6;

  // 24 staging slots (8 X, 8 Wg, 8 Wu), 6 per wave
  const char* sp[6]; size_t inc[6]; char* dstb[6];
#pragma unroll
  for (int s = 0; s < 6; ++s) {
    const int g = w * 6 + s;
    if (g < 8) {                       // X slot g: rows 16g..16g+15
      const int m = 16 * g + (lane >> 2);
      const int c = lane & 3;
      const int msrc = (m0 + m < cnt) ? (roff + m0 + m) : roff;
      sp[s] = (const char*)(X + (size_t)msrc * H_DIM + ((c ^ ((m >> 1) & 3)) << 3));
      inc[s] = (size_t)BK * 2;
      dstb[s] = xl + g * 1024;
    } else {                           // W slot: rows 4k..4k+3 of [32][64]
      const int ks = (g - 8) & 7;
      const int r = 4 * ks + (lane >> 4);
      const int cs = (lane & 15) ^ (((r >> 3) & 3) << 1);
      const float* Wb = (g < 16) ? Wg : Wu;
      sp[s] = (const char*)(Wb + (size_t)r * ldw + n0 + (cs << 2));
      inc[s] = (size_t)BK * ldw * 4;
      dstb[s] = ((g < 16) ? wgl : wul) + ks * 1024;
    }
  }

#define STAGE1(CUR) do {                                                 \
  _Pragma("unroll")                                                      \
  for (int s = 0; s < 6; ++s) {                                          \
    gl2lds16(sp[s], dstb[s] + (CUR) * 8192);                             \
    sp[s] += inc[s];                                                     \
  }                                                                      \
} while (0)

  const int q = lane >> 4, l15 = lane & 15;
  const int nl = w * 16 + l15;
  const int wro = q * 2048 + ((nl << 2) ^ (q << 5));          // W read base (bytes)
  const int xro = l15 * 64 + ((q ^ ((l15 >> 1) & 3)) << 4);   // X read base (bytes)

  f32x4 accg[8] = {};
  f32x4 accu[8] = {};

#define COMPUTE1(CUR) do {                                               \
  const char* _xb = xl + (CUR) * 8192 + xro;                             \
  const char* _wg = wgl + (CUR) * 8192 + wro;                            \
  const char* _wu = wul + (CUR) * 8192 + wro;                            \
  float _g32[8], _u32[8];                                                \
  _Pragma("unroll")                                                      \
  for (int j = 0; j < 8; ++j) {                                          \
    _g32[j] = *(const float*)(_wg + (j >> 2) * 1024 + (j & 3) * 256);    \
    _u32[j] = *(const float*)(_wu + (j >> 2) * 1024 + (j & 3) * 256);    \
  }                                                                      \
  bf16x8 _gf, _uf;                                                       \
  _Pragma("unroll")                                                      \
  for (int j = 0; j < 8; ++j) { _gf[j] = (__bf16)_g32[j];                \
                                _uf[j] = (__bf16)_u32[j]; }              \
  _Pragma("unroll")                                                      \
  for (int mb = 0; mb < 8; ++mb) {                                       \
    const u16x8 _xr = *(const u16x8*)(_xb + mb * 1024);                  \
    const bf16x8 _xf = __builtin_bit_cast(bf16x8, _xr);                  \
    accg[mb] = __builtin_amdgcn_mfma_f32_16x16x32_bf16(_gf, _xf, accg[mb], 0, 0, 0); \
    accu[mb] = __builtin_amdgcn_mfma_f32_16x16x32_bf16(_uf, _xf, accu[mb], 0, 0, 0); \
  }                                                                      \
} while (0)

  STAGE1(0);
  for (int t = 0; t < NSTEP1 - 1; ++t) {
    STAGE1((t + 1) & 1);                          // 6 loads for tile t+1
    asm volatile("s_waitcnt vmcnt(6)" ::: "memory");  // tile t done; t+1 in flight
    BAR();
    FENCE();
    COMPUTE1(t & 1);
    FENCE();
    BAR();                                        // protect buf (t+1)&1 from overwrite
  }
  asm volatile("s_waitcnt vmcnt(0)" ::: "memory");
  BAR();
  FENCE();
  COMPUTE1((NSTEP1 - 1) & 1);

  // D layout: row(n) = (lane>>4)*4 + reg, col(m) = lane&15
  const int nw = n0 + w * 16 + (q * 4);
#pragma unroll
  for (int mb = 0; mb < 8; ++mb) {
    const int m = m0 + mb * 16 + l15;
    if (m < cnt) {
      unsigned short o[4];
#pragma unroll
      for (int r = 0; r < 4; ++r) {
        const float g = accg[mb][r];
        const float u = accu[mb][r];
        const float sg = g / (1.f + __expf(-g));
        o[r] = f2bf(sg * u);
      }
      uint2 pk;
      pk.x = (unsigned)o[0] | ((unsigned)o[1] << 16);
      pk.y = (unsigned)o[2] | ((unsigned)o[3] << 16);
      *(uint2*)&OUT[(size_t)(roff + m) * I_DIM + nw] = pk;
    }
  }
}

// ================= GEMM2: out[t] (+)= act @ Wd =================
// Hybrid ring: X (L2-resident) double-buffered A=1; W (HBM stream) 4-deep A=2.
// vmcnt(6) steady state = {W(t+1), X(t+1), W(t+2)} allowed in flight.
__global__ __launch_bounds__(256) void gemm2_kernel(
    const unsigned short* __restrict__ ACT, const float* __restrict__ wd_base,
    float* __restrict__ OUT, const int* __restrict__ counts,
    const int* __restrict__ offsets, const int* __restrict__ perm,
    const int accumulate)
{
  const int e = blockIdx.z;
  const int cnt = counts ? counts[e] : NT;
  const int roff = offsets ? offsets[e] : 0;
  const int m0 = blockIdx.x * BM;
  if (m0 >= cnt) return;
  const int n0 = blockIdx.y * BN;
  const float* Wd = wd_base + (size_t)e * I_DIM * H_DIM;

  __shared__ char lds[49152];
  char* const xl  = lds;            // [2][8192]: ACT bf16 [128][32]
  char* const wdl = lds + 16384;    // [4][8192]: Wd f32 [32][64]

  const int tid = threadIdx.x, lane = tid & 63, w = tid >> 6;

  // X: 8 slots, 2/wave.  W: 8 slots, 2/wave.
  const char* spx[2]; char* dstx[2];
  const char* spw[2]; char* dstw[2];
#pragma unroll
  for (int s = 0; s < 2; ++s) {
    {
      const int g = w * 2 + s;
      const int m = 16 * g + (lane >> 2);
      const int c = lane & 3;
      const int msrc = (m0 + m < cnt) ? (roff + m0 + m) : roff;
      spx[s] = (const char*)(ACT + (size_t)msrc * I_DIM + ((c ^ ((m >> 1) & 3)) << 3));
      dstx[s] = xl + g * 1024;
    }
    {
      const int ks = w * 2 + s;
      const int r = 4 * ks + (lane >> 4);
      const int cs = (lane & 15) ^ (((r >> 3) & 3) << 1);
      spw[s] = (const char*)(Wd + (size_t)r * H_DIM + n0 + (cs << 2));
      dstw[s] = wdl + ks * 1024;
    }
  }
  const size_t incx = (size_t)BK * 2;
  const size_t incw = (size_t)BK * H_DIM * 4;

#define STAGEX2(CUR) do {                                                \
  _Pragma("unroll")                                                      \
  for (int s = 0; s < 2; ++s) {                                          \
    gl2lds16(spx[s], dstx[s] + (CUR) * 8192);                            \
    spx[s] += incx;                                                      \
  }                                                                      \
} while (0)

#define STAGEW2(CUR) do {                                                \
  _Pragma("unroll")                                                      \
  for (int s = 0; s < 2; ++s) {                                          \
    gl2lds16(spw[s], dstw[s] + (CUR) * 8192);                            \
    spw[s] += incw;                                                      \
  }                                                                      \
} while (0)

  const int q = lane >> 4, l15 = lane & 15;
  const int nl = w * 16 + l15;
  const int wro = q * 2048 + ((nl << 2) ^ (q << 5));
  const int xro = l15 * 64 + ((q ^ ((l15 >> 1) & 3)) << 4);

  f32x4 acc[8] = {};

#define COMPUTE2(BX, BW) do {                                            \
  const char* _xb = xl + (BX) * 8192 + xro;                              \
  const char* _wd = wdl + (BW) * 8192 + wro;                             \
  float _d32[8];                                                         \
  _Pragma("unroll")                                                      \
  for (int j = 0; j < 8; ++j)                                            \
    _d32[j] = *(const float*)(_wd + (j >> 2) * 1024 + (j & 3) * 256);    \
  bf16x8 _df;                                                            \
  _Pragma("unroll")                                                      \
  for (int j = 0; j < 8; ++j) _df[j] = (__bf16)_d32[j];                  \
  _Pragma("unroll")                                                      \
  for (int mb = 0; mb < 8; ++mb) {                                       \
    const u16x8 _xr = *(const u16x8*)(_xb + mb * 1024);                  \
    const bf16x8 _xf = __builtin_bit_cast(bf16x8, _xr);                  \
    acc[mb] = __builtin_amdgcn_mfma_f32_16x16x32_bf16(_df, _xf, acc[mb], 0, 0, 0); \
  }                                                                      \
} while (0)

  // prologue: X(0), W(0), W(1)
  STAGEX2(0);
  STAGEW2(0);
  STAGEW2(1);
  for (int t = 0; t < NSTEP2 - 2; ++t) {
    STAGEX2((t + 1) & 1);                         // X tile t+1 (2 loads)
    STAGEW2((t + 2) & 3);                         // W tile t+2 (2 loads)
    asm volatile("s_waitcnt vmcnt(6)" ::: "memory");  // X(t), W(t) done
    BAR();
    FENCE();
    COMPUTE2(t & 1, t & 3);
    FENCE();
    BAR();
  }
  // t = NSTEP2-2: no W stage left
  STAGEX2((NSTEP2 - 1) & 1);
  asm volatile("s_waitcnt vmcnt(4)" ::: "memory");
  BAR();
  FENCE();
  COMPUTE2((NSTEP2 - 2) & 1, (NSTEP2 - 2) & 3);
  FENCE();
  BAR();
  // t = NSTEP2-1
  asm volatile("s_waitcnt vmcnt(0)" ::: "memory");
  BAR();
  FENCE();
  COMPUTE2((NSTEP2 - 1) & 1, (NSTEP2 - 1) & 3);

  const int nw = n0 + w * 16 + (q * 4);
#pragma unroll
  for (int mb = 0; mb < 8; ++mb) {
    const int m = m0 + mb * 16 + l15;
    if (m < cnt) {
      const int t = perm ? perm[roff + m] : m;
      float* orow = OUT + (size_t)t * H_DIM + nw;
      f32x4 v = acc[mb];
      if (accumulate) {
        const f32x4 old = *(const f32x4*)orow;
        v += old;
      }
      *(f32x4*)orow = v;
    }
  }
}

extern "C" void kernel_launch(void* const* d_in, const int* in_sizes, int n_in,
                              void* d_out, int out_size, void* d_ws, size_t ws_size,
                              hipStream_t stream)
{
  const float* x   = (const float*)d_in[0];
  const float* rw  = (const float*)d_in[1];
  const float* gup = (const float*)d_in[2];
  const float* dwn = (const float*)d_in[3];
  const float* sgw = (const float*)d_in[4];
  const float* suw = (const float*)d_in[5];
  const float* sdw = (const float*)d_in[6];
  float* out = (float*)d_out;
  float* rs_out = out + (size_t)NT * H_DIM;   // router_scores [E][T] after out [T][H]

  char* ws = (char*)d_ws;
  int* counts   = (int*)ws;               // 32 B
  int* cursor   = (int*)(ws + 32);        // 32 B
  int* offsets  = (int*)(ws + 64);        // 32 B
  int* expert_of = (int*)(ws + 128);      // 4 KB
  float* score_of = (float*)(ws + 128 + 4096);
  int* perm     = (int*)(ws + 128 + 8192);
  unsigned short* xb    = (unsigned short*)(ws + 16384);       // [T][H] bf16 (4 MB)
  unsigned short* xs    = xb + (size_t)NT * H_DIM;             // grouped scaled (4 MB)
  unsigned short* act_s = xs + (size_t)NT * H_DIM;             // [T][I] bf16 (8 MB)
  unsigned short* act_r = act_s + (size_t)NT * I_DIM;          // [T][I] bf16 (8 MB)

  hipMemsetAsync(counts, 0, 64, stream);
  router_kernel<<<dim3(NT / 4), dim3(256), 0, stream>>>(x, rw, rs_out, expert_of, score_of, counts);
  offsets_kernel<<<dim3(1), dim3(64), 0, stream>>>(counts, offsets, cursor);
  scatter_kernel<<<dim3(NT / 256), dim3(256), 0, stream>>>(expert_of, offsets, cursor, perm);
  gather_kernel<<<dim3(NT), dim3(256), 0, stream>>>(x, perm, score_of, xb, xs);
  gemm1_kernel<<<dim3(NT / BM, I_DIM / BN, NE + 1), dim3(256), 0, stream>>>(
      xs, xb, gup, sgw, suw, act_r, act_s, counts, offsets);
  gemm2_kernel<<<dim3(NT / BM, H_DIM / BN, 1), dim3(256), 0, stream>>>(
      act_s, sdw, out, nullptr, nullptr, nullptr, 0);
  gemm2_kernel<<<dim3(NT / BM, H_DIM / BN, NE), dim3(256), 0, stream>>>(
      act_r, dwn, out, counts, offsets, perm, 1);
}

// Round 6
// 1097.857 us; speedup vs baseline: 2.5611x; 1.0035x over previous
//
#include <hip/hip_runtime.h>
#include <hip/hip_bf16.h>

#define H_DIM 2048
#define I_DIM 4096
#define NE 8
#define NT 1024

#define BM 128
#define BN 64
#define BK 32

#define NSTEP1 (H_DIM / BK)   // 64
#define NSTEP2 (I_DIM / BK)   // 128

typedef __bf16 bf16x8 __attribute__((ext_vector_type(8)));
typedef float f32x4 __attribute__((ext_vector_type(4)));
typedef unsigned short u16x8 __attribute__((ext_vector_type(8)));

__device__ __forceinline__ unsigned short f2bf(float f) {
  return __builtin_bit_cast(unsigned short, (__bf16)f);
}

// async global->LDS, 16B per lane; LDS dest = wave-uniform base + lane*16
__device__ __forceinline__ void gl2lds16(const void* g, void* l) {
  __builtin_amdgcn_global_load_lds(
      (const __attribute__((address_space(1))) unsigned int*)g,
      (__attribute__((address_space(3))) unsigned int*)l, 16, 0, 0);
}

#define FENCE() asm volatile("" ::: "memory")
#define BAR() __builtin_amdgcn_s_barrier()

// ---------------- router: 1 wave per token ----------------
__global__ __launch_bounds__(256) void router_kernel(
    const float* __restrict__ x, const float* __restrict__ rw,
    float* __restrict__ rs_out, int* __restrict__ expert_of,
    float* __restrict__ score_of, int* __restrict__ counts)
{
  const int lane = threadIdx.x & 63;
  const int wv = threadIdx.x >> 6;
  const int t = blockIdx.x * 4 + wv;
  float acc[NE];
#pragma unroll
  for (int e = 0; e < NE; ++e) acc[e] = 0.f;
  const float* xr = x + (size_t)t * H_DIM;
  for (int h0 = 0; h0 < H_DIM; h0 += 64) {
    const float xv = xr[h0 + lane];
    const float* rwp = rw + (size_t)(h0 + lane) * NE;
    const f32x4 r0 = *(const f32x4*)rwp;
    const f32x4 r1 = *(const f32x4*)(rwp + 4);
#pragma unroll
    for (int e = 0; e < 4; ++e) { acc[e] += xv * r0[e]; acc[e + 4] += xv * r1[e]; }
  }
#pragma unroll
  for (int e = 0; e < NE; ++e) {
    acc[e] += __shfl_xor(acc[e], 32, 64);
    acc[e] += __shfl_xor(acc[e], 16, 64);
    acc[e] += __shfl_xor(acc[e], 8, 64);
    acc[e] += __shfl_xor(acc[e], 4, 64);
    acc[e] += __shfl_xor(acc[e], 2, 64);
    acc[e] += __shfl_xor(acc[e], 1, 64);
  }
  int best = 0; float bv = acc[0];
#pragma unroll
  for (int e = 1; e < NE; ++e) if (acc[e] > bv) { bv = acc[e]; best = e; }
  const float score = 1.f / (1.f + __expf(-bv));
  if (lane < NE) rs_out[(size_t)lane * NT + t] = (lane == best) ? score : 0.f;
  if (lane == 0) {
    expert_of[t] = best;
    score_of[t] = score;
    atomicAdd(&counts[best], 1);
  }
}

// ---------------- offsets ----------------
__global__ void offsets_kernel(const int* __restrict__ counts,
                               int* __restrict__ offsets, int* __restrict__ cursor)
{
  if (threadIdx.x == 0) {
    int run = 0;
#pragma unroll
    for (int e = 0; e < NE; ++e) { offsets[e] = run; run += counts[e]; cursor[e] = 0; }
  }
}

// ---------------- scatter ----------------
__global__ void scatter_kernel(const int* __restrict__ expert_of,
                               const int* __restrict__ offsets,
                               int* __restrict__ cursor, int* __restrict__ perm)
{
  const int t = blockIdx.x * 256 + threadIdx.x;
  const int e = expert_of[t];
  const int p = atomicAdd(&cursor[e], 1);
  perm[offsets[e] + p] = t;
}

// ---------------- gather ----------------
__global__ __launch_bounds__(256) void gather_kernel(
    const float* __restrict__ x, const int* __restrict__ perm,
    const float* __restrict__ score_of, unsigned short* __restrict__ xb,
    unsigned short* __restrict__ xs)
{
  const int b = blockIdx.x;
  const int c = threadIdx.x * 8;
  const int src = perm[b];
  const float s = score_of[src];
  const float* xrow = x + (size_t)b * H_DIM + c;
  const float* srow = x + (size_t)src * H_DIM + c;
  u16x8 vb, vs;
#pragma unroll
  for (int j = 0; j < 8; ++j) {
    vb[j] = f2bf(xrow[j]);
    vs[j] = f2bf(srow[j] * s);
  }
  *(u16x8*)&xb[(size_t)b * H_DIM + c] = vb;
  *(u16x8*)&xs[(size_t)b * H_DIM + c] = vs;
}

// ================= GEMM1: act = silu(X@Wg) * (X@Wu) =================
// T3/T4: double-buffer, stage(t+1) issued before compute(t); counted
// s_waitcnt vmcnt(6) (next tile's 6 loads STAY IN FLIGHT across the barrier),
// raw s_barrier (no compiler vmcnt(0) drain).  Two barriers/iter (D=2).
__global__ __launch_bounds__(256) void gemm1_kernel(
    const unsigned short* __restrict__ xs, const unsigned short* __restrict__ xb,
    const float* __restrict__ gup, const float* __restrict__ sgw,
    const float* __restrict__ suw, unsigned short* __restrict__ act_r,
    unsigned short* __restrict__ act_s, const int* __restrict__ counts,
    const int* __restrict__ offsets)
{
  const int e = blockIdx.z;
  int cnt, roff; size_t ldw;
  const unsigned short* X; const float* Wg; const float* Wu; unsigned short* OUT;
  if (e < NE) {
    cnt = counts[e]; roff = offsets[e]; ldw = 2 * I_DIM;
    X = xs; Wg = gup + (size_t)e * H_DIM * 2 * I_DIM; Wu = Wg + I_DIM; OUT = act_r;
  } else {
    cnt = NT; roff = 0; ldw = I_DIM;
    X = xb; Wg = sgw; Wu = suw; OUT = act_s;
  }
  const int m0 = blockIdx.x * BM;
  if (m0 >= cnt) return;
  const int n0 = blockIdx.y * BN;

  __shared__ char lds[49152];
  char* const xl  = lds;            // [2][8192]: X bf16 [128][32]
  char* const wgl = lds + 16384;    // [2][8192]: Wg f32 [32][64]
  char* const wul = lds + 32768;    // [2][8192]: Wu f32 [32][64]

  const int tid = threadIdx.x, lane = tid & 63, w = tid >> 6;

  // 24 staging slots (8 X, 8 Wg, 8 Wu), 6 per wave
  const char* sp[6]; size_t inc[6]; char* dstb[6];
#pragma unroll
  for (int s = 0; s < 6; ++s) {
    const int g = w * 6 + s;
    if (g < 8) {                       // X slot g: rows 16g..16g+15
      const int m = 16 * g + (lane >> 2);
      const int c = lane & 3;
      const int msrc = (m0 + m < cnt) ? (roff + m0 + m) : roff;
      sp[s] = (const char*)(X + (size_t)msrc * H_DIM + ((c ^ ((m >> 1) & 3)) << 3));
      inc[s] = (size_t)BK * 2;
      dstb[s] = xl + g * 1024;
    } else {                           // W slot: rows 4k..4k+3 of [32][64]
      const int ks = (g - 8) & 7;
      const int r = 4 * ks + (lane >> 4);
      const int cs = (lane & 15) ^ (((r >> 3) & 3) << 1);
      const float* Wb = (g < 16) ? Wg : Wu;
      sp[s] = (const char*)(Wb + (size_t)r * ldw + n0 + (cs << 2));
      inc[s] = (size_t)BK * ldw * 4;
      dstb[s] = ((g < 16) ? wgl : wul) + ks * 1024;
    }
  }

#define STAGE1(CUR) do {                                                 \
  _Pragma("unroll")                                                      \
  for (int s = 0; s < 6; ++s) {                                          \
    gl2lds16(sp[s], dstb[s] + (CUR) * 8192);                             \
    sp[s] += inc[s];                                                     \
  }                                                                      \
} while (0)

  const int q = lane >> 4, l15 = lane & 15;
  const int nl = w * 16 + l15;
  const int wro = q * 2048 + ((nl << 2) ^ (q << 5));          // W read base (bytes)
  const int xro = l15 * 64 + ((q ^ ((l15 >> 1) & 3)) << 4);   // X read base (bytes)

  f32x4 accg[8] = {};
  f32x4 accu[8] = {};

#define COMPUTE1(CUR) do {                                               \
  const char* _xb = xl + (CUR) * 8192 + xro;                             \
  const char* _wg = wgl + (CUR) * 8192 + wro;                            \
  const char* _wu = wul + (CUR) * 8192 + wro;                            \
  float _g32[8], _u32[8];                                                \
  _Pragma("unroll")                                                      \
  for (int j = 0; j < 8; ++j) {                                          \
    _g32[j] = *(const float*)(_wg + (j >> 2) * 1024 + (j & 3) * 256);    \
    _u32[j] = *(const float*)(_wu + (j >> 2) * 1024 + (j & 3) * 256);    \
  }                                                                      \
  bf16x8 _gf, _uf;                                                       \
  _Pragma("unroll")                                                      \
  for (int j = 0; j < 8; ++j) { _gf[j] = (__bf16)_g32[j];                \
                                _uf[j] = (__bf16)_u32[j]; }              \
  _Pragma("unroll")                                                      \
  for (int mb = 0; mb < 8; ++mb) {                                       \
    const u16x8 _xr = *(const u16x8*)(_xb + mb * 1024);                  \
    const bf16x8 _xf = __builtin_bit_cast(bf16x8, _xr);                  \
    accg[mb] = __builtin_amdgcn_mfma_f32_16x16x32_bf16(_gf, _xf, accg[mb], 0, 0, 0); \
    accu[mb] = __builtin_amdgcn_mfma_f32_16x16x32_bf16(_uf, _xf, accu[mb], 0, 0, 0); \
  }                                                                      \
} while (0)

  STAGE1(0);
  for (int t = 0; t < NSTEP1 - 1; ++t) {
    STAGE1((t + 1) & 1);                          // 6 loads for tile t+1
    asm volatile("s_waitcnt vmcnt(6)" ::: "memory");  // tile t done; t+1 in flight
    BAR();
    FENCE();
    COMPUTE1(t & 1);
    FENCE();
    BAR();                                        // protect buf (t+1)&1 from overwrite
  }
  asm volatile("s_waitcnt vmcnt(0)" ::: "memory");
  BAR();
  FENCE();
  COMPUTE1((NSTEP1 - 1) & 1);

  // D layout: row(n) = (lane>>4)*4 + reg, col(m) = lane&15
  const int nw = n0 + w * 16 + (q * 4);
#pragma unroll
  for (int mb = 0; mb < 8; ++mb) {
    const int m = m0 + mb * 16 + l15;
    if (m < cnt) {
      unsigned short o[4];
#pragma unroll
      for (int r = 0; r < 4; ++r) {
        const float g = accg[mb][r];
        const float u = accu[mb][r];
        const float sg = g / (1.f + __expf(-g));
        o[r] = f2bf(sg * u);
      }
      uint2 pk;
      pk.x = (unsigned)o[0] | ((unsigned)o[1] << 16);
      pk.y = (unsigned)o[2] | ((unsigned)o[3] << 16);
      *(uint2*)&OUT[(size_t)(roff + m) * I_DIM + nw] = pk;
    }
  }
}

// ================= GEMM2: out[t] (+)= act @ Wd =================
// Hybrid ring: X (L2-resident) double-buffered A=1; W (HBM stream) 4-deep A=2.
// vmcnt(6) steady state = {W(t+1), X(t+1), W(t+2)} allowed in flight.
__global__ __launch_bounds__(256) void gemm2_kernel(
    const unsigned short* __restrict__ ACT, const float* __restrict__ wd_base,
    float* __restrict__ OUT, const int* __restrict__ counts,
    const int* __restrict__ offsets, const int* __restrict__ perm,
    const int accumulate)
{
  const int e = blockIdx.z;
  const int cnt = counts ? counts[e] : NT;
  const int roff = offsets ? offsets[e] : 0;
  const int m0 = blockIdx.x * BM;
  if (m0 >= cnt) return;
  const int n0 = blockIdx.y * BN;
  const float* Wd = wd_base + (size_t)e * I_DIM * H_DIM;

  __shared__ char lds[49152];
  char* const xl  = lds;            // [2][8192]: ACT bf16 [128][32]
  char* const wdl = lds + 16384;    // [4][8192]: Wd f32 [32][64]

  const int tid = threadIdx.x, lane = tid & 63, w = tid >> 6;

  // X: 8 slots, 2/wave.  W: 8 slots, 2/wave.
  const char* spx[2]; char* dstx[2];
  const char* spw[2]; char* dstw[2];
#pragma unroll
  for (int s = 0; s < 2; ++s) {
    {
      const int g = w * 2 + s;
      const int m = 16 * g + (lane >> 2);
      const int c = lane & 3;
      const int msrc = (m0 + m < cnt) ? (roff + m0 + m) : roff;
      spx[s] = (const char*)(ACT + (size_t)msrc * I_DIM + ((c ^ ((m >> 1) & 3)) << 3));
      dstx[s] = xl + g * 1024;
    }
    {
      const int ks = w * 2 + s;
      const int r = 4 * ks + (lane >> 4);
      const int cs = (lane & 15) ^ (((r >> 3) & 3) << 1);
      spw[s] = (const char*)(Wd + (size_t)r * H_DIM + n0 + (cs << 2));
      dstw[s] = wdl + ks * 1024;
    }
  }
  const size_t incx = (size_t)BK * 2;
  const size_t incw = (size_t)BK * H_DIM * 4;

#define STAGEX2(CUR) do {                                                \
  _Pragma("unroll")                                                      \
  for (int s = 0; s < 2; ++s) {                                          \
    gl2lds16(spx[s], dstx[s] + (CUR) * 8192);                            \
    spx[s] += incx;                                                      \
  }                                                                      \
} while (0)

#define STAGEW2(CUR) do {                                                \
  _Pragma("unroll")                                                      \
  for (int s = 0; s < 2; ++s) {                                          \
    gl2lds16(spw[s], dstw[s] + (CUR) * 8192);                            \
    spw[s] += incw;                                                      \
  }                                                                      \
} while (0)

  const int q = lane >> 4, l15 = lane & 15;
  const int nl = w * 16 + l15;
  const int wro = q * 2048 + ((nl << 2) ^ (q << 5));
  const int xro = l15 * 64 + ((q ^ ((l15 >> 1) & 3)) << 4);

  f32x4 acc[8] = {};

#define COMPUTE2(BX, BW) do {                                            \
  const char* _xb = xl + (BX) * 8192 + xro;                              \
  const char* _wd = wdl + (BW) * 8192 + wro;                             \
  float _d32[8];                                                         \
  _Pragma("unroll")                                                      \
  for (int j = 0; j < 8; ++j)                                            \
    _d32[j] = *(const float*)(_wd + (j >> 2) * 1024 + (j & 3) * 256);    \
  bf16x8 _df;                                                            \
  _Pragma("unroll")                                                      \
  for (int j = 0; j < 8; ++j) _df[j] = (__bf16)_d32[j];                  \
  _Pragma("unroll")                                                      \
  for (int mb = 0; mb < 8; ++mb) {                                       \
    const u16x8 _xr = *(const u16x8*)(_xb + mb * 1024);                  \
    const bf16x8 _xf = __builtin_bit_cast(bf16x8, _xr);                  \
    acc[mb] = __builtin_amdgcn_mfma_f32_16x16x32_bf16(_df, _xf, acc[mb], 0, 0, 0); \
  }                                                                      \
} while (0)

  // prologue: X(0), W(0), W(1)
  STAGEX2(0);
  STAGEW2(0);
  STAGEW2(1);
  for (int t = 0; t < NSTEP2 - 2; ++t) {
    STAGEX2((t + 1) & 1);                         // X tile t+1 (2 loads)
    STAGEW2((t + 2) & 3);                         // W tile t+2 (2 loads)
    asm volatile("s_waitcnt vmcnt(6)" ::: "memory");  // X(t), W(t) done
    BAR();
    FENCE();
    COMPUTE2(t & 1, t & 3);
    FENCE();
    BAR();
  }
  // t = NSTEP2-2: no W stage left
  STAGEX2((NSTEP2 - 1) & 1);
  asm volatile("s_waitcnt vmcnt(4)" ::: "memory");
  BAR();
  FENCE();
  COMPUTE2((NSTEP2 - 2) & 1, (NSTEP2 - 2) & 3);
  FENCE();
  BAR();
  // t = NSTEP2-1
  asm volatile("s_waitcnt vmcnt(0)" ::: "memory");
  BAR();
  FENCE();
  COMPUTE2((NSTEP2 - 1) & 1, (NSTEP2 - 1) & 3);

  const int nw = n0 + w * 16 + (q * 4);
#pragma unroll
  for (int mb = 0; mb < 8; ++mb) {
    const int m = m0 + mb * 16 + l15;
    if (m < cnt) {
      const int t = perm ? perm[roff + m] : m;
      float* orow = OUT + (size_t)t * H_DIM + nw;
      f32x4 v = acc[mb];
      if (accumulate) {
        const f32x4 old = *(const f32x4*)orow;
        v += old;
      }
      *(f32x4*)orow = v;
    }
  }
}

extern "C" void kernel_launch(void* const* d_in, const int* in_sizes, int n_in,
                              void* d_out, int out_size, void* d_ws, size_t ws_size,
                              hipStream_t stream)
{
  const float* x   = (const float*)d_in[0];
  const float* rw  = (const float*)d_in[1];
  const float* gup = (const float*)d_in[2];
  const float* dwn = (const float*)d_in[3];
  const float* sgw = (const float*)d_in[4];
  const float* suw = (const float*)d_in[5];
  const float* sdw = (const float*)d_in[6];
  float* out = (float*)d_out;
  float* rs_out = out + (size_t)NT * H_DIM;   // router_scores [E][T] after out [T][H]

  char* ws = (char*)d_ws;
  int* counts   = (int*)ws;               // 32 B
  int* cursor   = (int*)(ws + 32);        // 32 B
  int* offsets  = (int*)(ws + 64);        // 32 B
  int* expert_of = (int*)(ws + 128);      // 4 KB
  float* score_of = (float*)(ws + 128 + 4096);
  int* perm     = (int*)(ws + 128 + 8192);
  unsigned short* xb    = (unsigned short*)(ws + 16384);       // [T][H] bf16 (4 MB)
  unsigned short* xs    = xb + (size_t)NT * H_DIM;             // grouped scaled (4 MB)
  unsigned short* act_s = xs + (size_t)NT * H_DIM;             // [T][I] bf16 (8 MB)
  unsigned short* act_r = act_s + (size_t)NT * I_DIM;          // [T][I] bf16 (8 MB)

  hipMemsetAsync(counts, 0, 64, stream);
  router_kernel<<<dim3(NT / 4), dim3(256), 0, stream>>>(x, rw, rs_out, expert_of, score_of, counts);
  offsets_kernel<<<dim3(1), dim3(64), 0, stream>>>(counts, offsets, cursor);
  scatter_kernel<<<dim3(NT / 256), dim3(256), 0, stream>>>(expert_of, offsets, cursor, perm);
  gather_kernel<<<dim3(NT), dim3(256), 0, stream>>>(x, perm, score_of, xb, xs);
  gemm1_kernel<<<dim3(NT / BM, I_DIM / BN, NE + 1), dim3(256), 0, stream>>>(
      xs, xb, gup, sgw, suw, act_r, act_s, counts, offsets);
  gemm2_kernel<<<dim3(NT / BM, H_DIM / BN, 1), dim3(256), 0, stream>>>(
      act_s, sdw, out, nullptr, nullptr, nullptr, 0);
  gemm2_kernel<<<dim3(NT / BM, H_DIM / BN, NE), dim3(256), 0, stream>>>(
      act_r, dwn, out, counts, offsets, perm, 1);
}